// Round 8
// baseline (241.791 us; speedup 1.0000x reference)
//
#include <hip/hip_runtime.h>
#include <hip/hip_fp16.h>

// ---------------------------------------------------------------------------
// 2-layer tanh RNN, B=8192, S=512, H=16 via MFMA 16x16x16_f16, layer-skewed,
// TWO independent batch-group chains per wave (32 batches/wave, 256 waves).
// Round-7 analysis: 436 cyc/step with only 161 issue -> 275 cyc exposed
// latency per step (1 wave/SIMD max, nothing to fill stalls). Chain B's
// instructions fill chain A's mfma/tanh latency: superstep ~ max(CP~150,
// issue 2x161~322) for TWO steps.
// Skewed step (per chain): consumes Bh0=H0[t], Bh1=H1[t-1]:
//   H0[t+1] = tanh(Whh0*H0[t] + wih0*x_{t+1} + b0)   (mfma a)
//   H1[t]   = tanh(Wih1*H0[t] + b1  +  Whh1*H1[t-1]) (mfma d + mfma e)
// C/D rows (lane>>4)*4+r == B k-slots -> tanh->pack->B is lane-local, no DPP.
// ---------------------------------------------------------------------------

typedef __fp16 f16x4 __attribute__((ext_vector_type(4)));
typedef __fp16 f16x2 __attribute__((ext_vector_type(2)));
typedef float  f32x4 __attribute__((ext_vector_type(4)));

__device__ __forceinline__ float tanh_fast(float v) {
    // tanh(v) = 1 - 2/(exp(2v)+1); exp via v_exp_f32 (2^x): 2*log2(e)
    float e = __builtin_amdgcn_exp2f(v * 2.8853900817779268f);
    float r = __builtin_amdgcn_rcpf(e + 1.0f);
    return fmaf(-2.0f, r, 1.0f);
}

__global__ __launch_bounds__(64, 1) void rnn2_mfma2(
    const float* __restrict__ x,
    const float* __restrict__ Wih0, const float* __restrict__ Whh0,
    const float* __restrict__ bih0, const float* __restrict__ bhh0,
    const float* __restrict__ Wih1, const float* __restrict__ Whh1,
    const float* __restrict__ bih1, const float* __restrict__ bhh1,
    const float* __restrict__ Wfc,  const float* __restrict__ bfc,
    float* __restrict__ out)
{
    const int lane = threadIdx.x & 63;
    const int q    = lane >> 4;     // quarter: k-slot / C-row group
    const int col  = lane & 15;     // batch column n; also A row m
    const int m4   = q * 4;
    const int b0A  = blockIdx.x * 32;
    const int b0B  = b0A + 16;

    // A fragments: A[m][k], m = col, k = m4 + i  (f16 RNE) — shared by chains
    f16x4 Ahh0, Aih1, Ahh1;
#pragma unroll
    for (int i = 0; i < 4; ++i) {
        Ahh0[i] = (__fp16)Whh0[col * 16 + m4 + i];
        Aih1[i] = (__fp16)Wih1[col * 16 + m4 + i];
        Ahh1[i] = (__fp16)Whh1[col * 16 + m4 + i];
    }
    // per-lane constants for C rows m = m4 + r — shared by chains
    float wih0q[4], b0q[4], wfcq[4];
    f32x4 cb1;
#pragma unroll
    for (int r = 0; r < 4; ++r) {
        wih0q[r] = Wih0[m4 + r];                    // W_ih0 is [16][1]
        b0q[r]   = bih0[m4 + r] + bhh0[m4 + r];
        cb1[r]   = bih1[m4 + r] + bhh1[m4 + r];
        wfcq[r]  = Wfc[m4 + r];
    }
    const float* __restrict__ xrowA = x + (size_t)(b0A + col) * 512;
    const float* __restrict__ xrowB = x + (size_t)(b0B + col) * 512;

    const f32x4 zero4 = {0.f, 0.f, 0.f, 0.f};
    f16x4 Bh0A, Bh1A = {0, 0, 0, 0}, Bh0B, Bh1B = {0, 0, 0, 0};
    float uA0 = 0.f, uA1 = 0.f, uA2 = 0.f, uA3 = 0.f;
    float uB0 = 0.f, uB1 = 0.f, uB2 = 0.f, uB3 = 0.f;

    // ---- prologue: H0[0] = tanh(wih0*x_0 + b0)  (h0_prev = 0), per chain ----
#define PROLOG(SFX, xrow)                                                     \
  {                                                                           \
    const float xt = (xrow)[0];                                               \
    const float s0 = tanh_fast(fmaf(wih0q[0], xt, b0q[0]));                   \
    const float s1 = tanh_fast(fmaf(wih0q[1], xt, b0q[1]));                   \
    const float s2 = tanh_fast(fmaf(wih0q[2], xt, b0q[2]));                   \
    const float s3 = tanh_fast(fmaf(wih0q[3], xt, b0q[3]));                   \
    f16x2 p0 = __builtin_amdgcn_cvt_pkrtz(s0, s1);                            \
    f16x2 p1 = __builtin_amdgcn_cvt_pkrtz(s2, s3);                            \
    Bh0##SFX = __builtin_shufflevector(p0, p1, 0, 1, 2, 3);                   \
  }
    PROLOG(A, xrowA)
    PROLOG(B, xrowB)

    // x buffers hold x[t+1] for the 8 steps of the current chunk
    float xcA[8], xnA[8], xcB[8], xnB[8];
#pragma unroll
    for (int i = 0; i < 8; ++i) { xcA[i] = xrowA[1 + i]; xcB[i] = xrowB[1 + i]; }

    // phase 1 of a skewed step: biases + 3 independent mfmas (no result use)
#define STEP_MM(SFX, xt1)                                                     \
    f32x4 c0##SFX;                                                            \
    c0##SFX[0] = fmaf(wih0q[0], (xt1), b0q[0]);                               \
    c0##SFX[1] = fmaf(wih0q[1], (xt1), b0q[1]);                               \
    c0##SFX[2] = fmaf(wih0q[2], (xt1), b0q[2]);                               \
    c0##SFX[3] = fmaf(wih0q[3], (xt1), b0q[3]);                               \
    f32x4 a##SFX = __builtin_amdgcn_mfma_f32_16x16x16f16(Ahh0, Bh0##SFX, c0##SFX, 0, 0, 0); \
    f32x4 d##SFX = __builtin_amdgcn_mfma_f32_16x16x16f16(Aih1, Bh0##SFX, cb1, 0, 0, 0);     \
    f32x4 e##SFX = __builtin_amdgcn_mfma_f32_16x16x16f16(Ahh1, Bh1##SFX, zero4, 0, 0, 0);

    // phase 2: tanh + pack back into B operands
#define STEP_TANH(SFX)                                                        \
    u##SFX##0 = tanh_fast(d##SFX[0] + e##SFX[0]);                             \
    u##SFX##1 = tanh_fast(d##SFX[1] + e##SFX[1]);                             \
    u##SFX##2 = tanh_fast(d##SFX[2] + e##SFX[2]);                             \
    u##SFX##3 = tanh_fast(d##SFX[3] + e##SFX[3]);                             \
    {                                                                         \
      f16x2 r0 = __builtin_amdgcn_cvt_pkrtz(u##SFX##0, u##SFX##1);            \
      f16x2 r1 = __builtin_amdgcn_cvt_pkrtz(u##SFX##2, u##SFX##3);            \
      Bh1##SFX = __builtin_shufflevector(r0, r1, 0, 1, 2, 3);                 \
      const float s0 = tanh_fast(a##SFX[0]);                                  \
      const float s1 = tanh_fast(a##SFX[1]);                                  \
      const float s2 = tanh_fast(a##SFX[2]);                                  \
      const float s3 = tanh_fast(a##SFX[3]);                                  \
      f16x2 p0 = __builtin_amdgcn_cvt_pkrtz(s0, s1);                          \
      f16x2 p1 = __builtin_amdgcn_cvt_pkrtz(s2, s3);                          \
      Bh0##SFX = __builtin_shufflevector(p0, p1, 0, 1, 2, 3);                 \
    }

    for (int t0 = 0; t0 < 512; t0 += 8) {
        // prefetch next chunk's x[t+1] values (wraps at end; extra unused)
#pragma unroll
        for (int i = 0; i < 8; ++i) {
            const int tn = (t0 + 9 + i) & 511;
            xnA[i] = xrowA[tn];
            xnB[i] = xrowB[tn];
        }
        // 8 supersteps: each advances chain A and chain B by one timestep.
        // (t=511 consumes a wrapped x value -> computes unused H0[512].)
#pragma unroll
        for (int j = 0; j < 8; ++j) {
            STEP_MM(A, xcA[j])
            STEP_MM(B, xcB[j])
            STEP_TANH(A)
            STEP_TANH(B)
        }
#pragma unroll
        for (int i = 0; i < 8; ++i) { xcA[i] = xnA[i]; xcB[i] = xnB[i]; }
    }

    // out[b] = Wfc . H1[511] + bfc — quarter-partial then sum quarters
    float vA = uA0 * wfcq[0] + uA1 * wfcq[1] + uA2 * wfcq[2] + uA3 * wfcq[3];
    float vB = uB0 * wfcq[0] + uB1 * wfcq[1] + uB2 * wfcq[2] + uB3 * wfcq[3];
    vA += __shfl_xor(vA, 16, 64);
    vA += __shfl_xor(vA, 32, 64);
    vB += __shfl_xor(vB, 16, 64);
    vB += __shfl_xor(vB, 32, 64);
    if (lane < 16) {
        out[b0A + lane] = vA + bfc[0];
        out[b0B + lane] = vB + bfc[0];
    }
}

extern "C" void kernel_launch(void* const* d_in, const int* in_sizes, int n_in,
                              void* d_out, int out_size, void* d_ws, size_t ws_size,
                              hipStream_t stream) {
    const float* x    = (const float*)d_in[0];
    const float* Wih0 = (const float*)d_in[1];
    const float* Whh0 = (const float*)d_in[2];
    const float* bih0 = (const float*)d_in[3];
    const float* bhh0 = (const float*)d_in[4];
    const float* Wih1 = (const float*)d_in[5];
    const float* Whh1 = (const float*)d_in[6];
    const float* bih1 = (const float*)d_in[7];
    const float* bhh1 = (const float*)d_in[8];
    const float* Wfc  = (const float*)d_in[9];
    const float* bfc  = (const float*)d_in[10];
    float* out = (float*)d_out;

    rnn2_mfma2<<<dim3(256), dim3(64), 0, stream>>>(
        x, Wih0, Whh0, bih0, bhh0, Wih1, Whh1, bih1, bhh1, Wfc, bfc, out);
}

// Round 10
// 197.613 us; speedup vs baseline: 1.2236x; 1.2236x over previous
//
#include <hip/hip_runtime.h>
#include <hip/hip_fp16.h>

// ---------------------------------------------------------------------------
// 2-layer tanh RNN, B=8192, S=512, H=16. MFMA 16x16x16_f16, PRODUCER/CONSUMER
// pipeline: wave0 = layer 0, wave1 = layer 1, H0 handed off through LDS with
// a 2-step skew (wave0 leads by 2), 4-slot rotation, 1 barrier/step.
// Round-8 lesson: independent work must be in DIFFERENT waves (issue ports /
// trans units are per-SIMD). Round-7 decomposition: 322 issue cyc/step, ~226
// from 16 transcendentals (~14 cyc each). Split halves per-wave trans to 8.
// Wave1 prefetches H0[s+1] during step s -> LDS latency never on the chain.
// 512 blocks x 128 thr = 1024 waves = 1/SIMD, all 4 trans units/CU busy.
// ---------------------------------------------------------------------------

typedef __fp16 f16x4 __attribute__((ext_vector_type(4)));
typedef __fp16 f16x2 __attribute__((ext_vector_type(2)));
typedef float  f32x4 __attribute__((ext_vector_type(4)));

__device__ __forceinline__ float tanh_fast(float v) {
    // tanh(v) = 1 - 2/(exp(2v)+1); exp via v_exp_f32 (2^x): 2*log2(e)
    float e = __builtin_amdgcn_exp2f(v * 2.8853900817779268f);
    float r = __builtin_amdgcn_rcpf(e + 1.0f);
    return fmaf(-2.0f, r, 1.0f);
}

__global__ __launch_bounds__(128, 1) void rnn2_pipe(
    const float* __restrict__ x,
    const float* __restrict__ Wih0, const float* __restrict__ Whh0,
    const float* __restrict__ bih0, const float* __restrict__ bhh0,
    const float* __restrict__ Wih1, const float* __restrict__ Whh1,
    const float* __restrict__ bih1, const float* __restrict__ bhh1,
    const float* __restrict__ Wfc,  const float* __restrict__ bfc,
    float* __restrict__ out)
{
    const int tid  = threadIdx.x;
    const int wid  = tid >> 6;      // 0 = layer-0 producer, 1 = layer-1 consumer
    const int lane = tid & 63;
    const int q    = lane >> 4;     // quarter: k-slot / C-row group
    const int col  = lane & 15;     // batch column n; also A row m
    const int m4   = q * 4;
    const int b0   = blockIdx.x * 16;

    // H0 handoff: B-operand fragments (8B/lane), 4-slot rotation
    __shared__ unsigned long long h0slot[4][64];

    // A fragments: A[m][k], m = col, k = m4 + i  (f16 RNE)
    f16x4 Ahh0, Aih1, Ahh1;
#pragma unroll
    for (int i = 0; i < 4; ++i) {
        Ahh0[i] = (__fp16)Whh0[col * 16 + m4 + i];
        Aih1[i] = (__fp16)Wih1[col * 16 + m4 + i];
        Ahh1[i] = (__fp16)Whh1[col * 16 + m4 + i];
    }
    // per-lane constants for C rows m = m4 + r
    float wih0q[4], b0q[4], wfcq[4];
    f32x4 cb1;
#pragma unroll
    for (int r = 0; r < 4; ++r) {
        wih0q[r] = Wih0[m4 + r];                    // W_ih0 is [16][1]
        b0q[r]   = bih0[m4 + r] + bhh0[m4 + r];
        cb1[r]   = bih1[m4 + r] + bhh1[m4 + r];
        wfcq[r]  = Wfc[m4 + r];
    }
    const float* __restrict__ xrow = x + (size_t)(b0 + col) * 512;
    const f32x4 zero4 = {0.f, 0.f, 0.f, 0.f};

    // producer state
    f16x4 Bh0;
    float xc[16], xn[16];
    // consumer state
    f16x4 h0cur, Bh1 = {0, 0, 0, 0};
    unsigned long long h0nxt = 0;
    float u0 = 0.f, u1 = 0.f, u2 = 0.f, u3 = 0.f;

    // ---- prologue (wave0): H0[0], H0[1] -> slots 0,1; preload x[2..17] ----
    if (wid == 0) {
        {
            const float x0 = xrow[0];
            f16x2 p0 = __builtin_amdgcn_cvt_pkrtz(
                tanh_fast(fmaf(wih0q[0], x0, b0q[0])),
                tanh_fast(fmaf(wih0q[1], x0, b0q[1])));
            f16x2 p1 = __builtin_amdgcn_cvt_pkrtz(
                tanh_fast(fmaf(wih0q[2], x0, b0q[2])),
                tanh_fast(fmaf(wih0q[3], x0, b0q[3])));
            Bh0 = __builtin_shufflevector(p0, p1, 0, 1, 2, 3);
        }
        h0slot[0][lane] = __builtin_bit_cast(unsigned long long, Bh0);
        {
            const float x1 = xrow[1];
            f32x4 c0;
            c0[0] = fmaf(wih0q[0], x1, b0q[0]);
            c0[1] = fmaf(wih0q[1], x1, b0q[1]);
            c0[2] = fmaf(wih0q[2], x1, b0q[2]);
            c0[3] = fmaf(wih0q[3], x1, b0q[3]);
            f32x4 a = __builtin_amdgcn_mfma_f32_16x16x16f16(Ahh0, Bh0, c0, 0, 0, 0);
            f16x2 p0 = __builtin_amdgcn_cvt_pkrtz(tanh_fast(a[0]), tanh_fast(a[1]));
            f16x2 p1 = __builtin_amdgcn_cvt_pkrtz(tanh_fast(a[2]), tanh_fast(a[3]));
            Bh0 = __builtin_shufflevector(p0, p1, 0, 1, 2, 3);
        }
        h0slot[1][lane] = __builtin_bit_cast(unsigned long long, Bh0);
#pragma unroll
        for (int i = 0; i < 16; ++i) xc[i] = xrow[(2 + i) & 511];
    }
    __syncthreads();
    if (wid == 1) h0cur = __builtin_bit_cast(f16x4, h0slot[0][lane]);

    // ---- main loop: iter s advances wave0 to H0[s+2], wave1 to H1[s] ----
    for (int t0 = 0; t0 < 512; t0 += 16) {
        if (wid == 0) {
            // prefetch next chunk's x[t+2] values (wraps at end; extras unused)
#pragma unroll
            for (int i = 0; i < 16; ++i) xn[i] = xrow[(t0 + 18 + i) & 511];
        }
#pragma unroll
        for (int j = 0; j < 16; ++j) {
            const int s = t0 + j;
            if (wid == 0) {
                // H0[s+2] = tanh(Whh0*H0[s+1] + wih0*x[s+2] + b0)
                const float xt = xc[j];
                f32x4 c0;
                c0[0] = fmaf(wih0q[0], xt, b0q[0]);
                c0[1] = fmaf(wih0q[1], xt, b0q[1]);
                c0[2] = fmaf(wih0q[2], xt, b0q[2]);
                c0[3] = fmaf(wih0q[3], xt, b0q[3]);
                f32x4 a = __builtin_amdgcn_mfma_f32_16x16x16f16(Ahh0, Bh0, c0, 0, 0, 0);
                f16x2 p0 = __builtin_amdgcn_cvt_pkrtz(tanh_fast(a[0]), tanh_fast(a[1]));
                f16x2 p1 = __builtin_amdgcn_cvt_pkrtz(tanh_fast(a[2]), tanh_fast(a[3]));
                Bh0 = __builtin_shufflevector(p0, p1, 0, 1, 2, 3);
                h0slot[(s + 2) & 3][lane] = __builtin_bit_cast(unsigned long long, Bh0);
            } else {
                // prefetch H0[s+1] (written at iter s-1, visible since barrier)
                h0nxt = h0slot[(s + 1) & 3][lane];
                // H1[s] = tanh(Wih1*H0[s] + b1 + Whh1*H1[s-1])
                f32x4 d = __builtin_amdgcn_mfma_f32_16x16x16f16(Aih1, h0cur, cb1, 0, 0, 0);
                f32x4 e = __builtin_amdgcn_mfma_f32_16x16x16f16(Ahh1, Bh1, zero4, 0, 0, 0);
                u0 = tanh_fast(d[0] + e[0]);
                u1 = tanh_fast(d[1] + e[1]);
                u2 = tanh_fast(d[2] + e[2]);
                u3 = tanh_fast(d[3] + e[3]);
                f16x2 r0 = __builtin_amdgcn_cvt_pkrtz(u0, u1);
                f16x2 r1 = __builtin_amdgcn_cvt_pkrtz(u2, u3);
                Bh1 = __builtin_shufflevector(r0, r1, 0, 1, 2, 3);
                h0cur = __builtin_bit_cast(f16x4, h0nxt);
            }
            __syncthreads();
        }
        if (wid == 0) {
#pragma unroll
            for (int i = 0; i < 16; ++i) xc[i] = xn[i];
        }
    }

    // ---- epilogue (wave1): out = Wfc . H1[511] + bfc ----
    if (wid == 1) {
        float v = u0 * wfcq[0] + u1 * wfcq[1] + u2 * wfcq[2] + u3 * wfcq[3];
        v += __shfl_xor(v, 16, 64);
        v += __shfl_xor(v, 32, 64);
        if (lane < 16) out[b0 + lane] = v + bfc[0];
    }
}

extern "C" void kernel_launch(void* const* d_in, const int* in_sizes, int n_in,
                              void* d_out, int out_size, void* d_ws, size_t ws_size,
                              hipStream_t stream) {
    const float* x    = (const float*)d_in[0];
    const float* Wih0 = (const float*)d_in[1];
    const float* Whh0 = (const float*)d_in[2];
    const float* bih0 = (const float*)d_in[3];
    const float* bhh0 = (const float*)d_in[4];
    const float* Wih1 = (const float*)d_in[5];
    const float* Whh1 = (const float*)d_in[6];
    const float* bih1 = (const float*)d_in[7];
    const float* bhh1 = (const float*)d_in[8];
    const float* Wfc  = (const float*)d_in[9];
    const float* bfc  = (const float*)d_in[10];
    float* out = (float*)d_out;

    rnn2_pipe<<<dim3(512), dim3(128), 0, stream>>>(
        x, Wih0, Whh0, bih0, bhh0, Wih1, Whh1, bih1, bhh1, Wfc, bfc, out);
}

// Round 11
// 167.592 us; speedup vs baseline: 1.4427x; 1.1791x over previous
//
#include <hip/hip_runtime.h>
#include <hip/hip_fp16.h>

// ---------------------------------------------------------------------------
// 2-layer tanh RNN, B=8192, S=512, H=16. MFMA 16x16x16_f16 producer/consumer
// pipeline with K=16 CHUNKED handoff (round-10 fix: per-step __syncthreads
// cost ~300+cyc was 435 cyc/step of stall; now 1 barrier per 16 steps).
// wave0 = layer 0: H0[p] = tanh(Whh0*H0[p-1] + wih0*x[p] + b0), writes LDS.
// wave1 = layer 1: H1[s] = tanh(Wih1*H0[s] + Whh1*H1[s-1] + b1), lags by 16.
// 32-slot (2x16) LDS double buffer: producer writes half while consumer
// reads the other half; consumer only touches slots written before the last
// barrier. Within-chunk slot prefetch (skip j=15 -> no race).
// Bh0 init 0 => mfma(W,0,c0)=c0 gives uniform p=0 step (tanh(c0)).
// 512 blocks x 128 thr = 1024 waves = 1/SIMD; trans (16cyc/op) split 8/wave.
// ---------------------------------------------------------------------------

typedef __fp16 f16x4 __attribute__((ext_vector_type(4)));
typedef __fp16 f16x2 __attribute__((ext_vector_type(2)));
typedef float  f32x4 __attribute__((ext_vector_type(4)));

__device__ __forceinline__ float tanh_fast(float v) {
    // tanh(v) = 1 - 2/(exp(2v)+1); exp via v_exp_f32 (2^x): 2*log2(e)
    float e = __builtin_amdgcn_exp2f(v * 2.8853900817779268f);
    float r = __builtin_amdgcn_rcpf(e + 1.0f);
    return fmaf(-2.0f, r, 1.0f);
}

__global__ __launch_bounds__(128, 1) void rnn2_pipek(
    const float* __restrict__ x,
    const float* __restrict__ Wih0, const float* __restrict__ Whh0,
    const float* __restrict__ bih0, const float* __restrict__ bhh0,
    const float* __restrict__ Wih1, const float* __restrict__ Whh1,
    const float* __restrict__ bih1, const float* __restrict__ bhh1,
    const float* __restrict__ Wfc,  const float* __restrict__ bfc,
    float* __restrict__ out)
{
    const int tid  = threadIdx.x;
    const int wid  = tid >> 6;      // 0 = layer-0 producer, 1 = layer-1 consumer
    const int lane = tid & 63;
    const int q    = lane >> 4;     // quarter: k-slot / C-row group
    const int col  = lane & 15;     // batch column n; also A row m
    const int m4   = q * 4;
    const int b0   = blockIdx.x * 16;

    // H0 handoff: B-fragments (8B/lane), 32 slots = 2 chunks of 16 (16 KB)
    __shared__ unsigned long long h0slot[32][64];

    // A fragments: A[m][k], m = col, k = m4 + i  (f16 RNE)
    f16x4 Ahh0, Aih1, Ahh1;
#pragma unroll
    for (int i = 0; i < 4; ++i) {
        Ahh0[i] = (__fp16)Whh0[col * 16 + m4 + i];
        Aih1[i] = (__fp16)Wih1[col * 16 + m4 + i];
        Ahh1[i] = (__fp16)Whh1[col * 16 + m4 + i];
    }
    // per-lane constants for C rows m = m4 + r
    float wih0q[4], b0q[4], wfcq[4];
    f32x4 cb1;
#pragma unroll
    for (int r = 0; r < 4; ++r) {
        wih0q[r] = Wih0[m4 + r];                    // W_ih0 is [16][1]
        b0q[r]   = bih0[m4 + r] + bhh0[m4 + r];
        cb1[r]   = bih1[m4 + r] + bhh1[m4 + r];
        wfcq[r]  = Wfc[m4 + r];
    }
    const float* __restrict__ xrow = x + (size_t)(b0 + col) * 512;
    const f32x4 zero4 = {0.f, 0.f, 0.f, 0.f};

    // producer state (H0[-1] = 0 -> first mfma passes c0 through)
    f16x4 Bh0 = {0, 0, 0, 0};
    float xc[16], xn[16];
    // consumer state
    f16x4 h0cur, Bh1 = {0, 0, 0, 0};
    float u0 = 0.f, u1 = 0.f, u2 = 0.f, u3 = 0.f;

    if (wid == 0) {
#pragma unroll
        for (int i = 0; i < 16; ++i) xc[i] = xrow[i];
    }

    // body i: producer runs chunk i (i<32), consumer runs chunk i-1 (i>=1).
    // One barrier per body. Consumer only reads slots written before the
    // previous barrier (producer leads by exactly one 16-step chunk).
    for (int i = 0; i <= 32; ++i) {
        if (wid == 0 && i < 32) {
            // prefetch next chunk's x (wraps at end; extras unused)
#pragma unroll
            for (int k2 = 0; k2 < 16; ++k2)
                xn[k2] = xrow[((i + 1) * 16 + k2) & 511];
#pragma unroll
            for (int j = 0; j < 16; ++j) {
                const int p = i * 16 + j;
                const float xt = xc[j];
                f32x4 c0;
                c0[0] = fmaf(wih0q[0], xt, b0q[0]);
                c0[1] = fmaf(wih0q[1], xt, b0q[1]);
                c0[2] = fmaf(wih0q[2], xt, b0q[2]);
                c0[3] = fmaf(wih0q[3], xt, b0q[3]);
                f32x4 a = __builtin_amdgcn_mfma_f32_16x16x16f16(Ahh0, Bh0, c0, 0, 0, 0);
                f16x2 p0 = __builtin_amdgcn_cvt_pkrtz(tanh_fast(a[0]), tanh_fast(a[1]));
                f16x2 p1 = __builtin_amdgcn_cvt_pkrtz(tanh_fast(a[2]), tanh_fast(a[3]));
                Bh0 = __builtin_shufflevector(p0, p1, 0, 1, 2, 3);
                h0slot[p & 31][lane] = __builtin_bit_cast(unsigned long long, Bh0);
            }
#pragma unroll
            for (int k2 = 0; k2 < 16; ++k2) xc[k2] = xn[k2];
        }
        if (wid == 1 && i >= 1) {
            const int c = i - 1;
            h0cur = __builtin_bit_cast(f16x4, h0slot[(c * 16) & 31][lane]);
            unsigned long long h0n_ = 0;
#pragma unroll
            for (int j = 0; j < 16; ++j) {
                // prefetch next step's H0 (same chunk only; j=15 reads at
                // next body start, after the barrier -> no race)
                if (j < 15) h0n_ = h0slot[(c * 16 + j + 1) & 31][lane];
                f32x4 d = __builtin_amdgcn_mfma_f32_16x16x16f16(Aih1, h0cur, cb1, 0, 0, 0);
                f32x4 e = __builtin_amdgcn_mfma_f32_16x16x16f16(Ahh1, Bh1, zero4, 0, 0, 0);
                u0 = tanh_fast(d[0] + e[0]);
                u1 = tanh_fast(d[1] + e[1]);
                u2 = tanh_fast(d[2] + e[2]);
                u3 = tanh_fast(d[3] + e[3]);
                f16x2 r0 = __builtin_amdgcn_cvt_pkrtz(u0, u1);
                f16x2 r1 = __builtin_amdgcn_cvt_pkrtz(u2, u3);
                Bh1 = __builtin_shufflevector(r0, r1, 0, 1, 2, 3);
                if (j < 15) h0cur = __builtin_bit_cast(f16x4, h0n_);
            }
        }
        __syncthreads();
    }

    // ---- epilogue (wave1): out = Wfc . H1[511] + bfc ----
    if (wid == 1) {
        float v = u0 * wfcq[0] + u1 * wfcq[1] + u2 * wfcq[2] + u3 * wfcq[3];
        v += __shfl_xor(v, 16, 64);
        v += __shfl_xor(v, 32, 64);
        if (lane < 16) out[b0 + lane] = v + bfc[0];
    }
}

extern "C" void kernel_launch(void* const* d_in, const int* in_sizes, int n_in,
                              void* d_out, int out_size, void* d_ws, size_t ws_size,
                              hipStream_t stream) {
    const float* x    = (const float*)d_in[0];
    const float* Wih0 = (const float*)d_in[1];
    const float* Whh0 = (const float*)d_in[2];
    const float* bih0 = (const float*)d_in[3];
    const float* bhh0 = (const float*)d_in[4];
    const float* Wih1 = (const float*)d_in[5];
    const float* Whh1 = (const float*)d_in[6];
    const float* bih1 = (const float*)d_in[7];
    const float* bhh1 = (const float*)d_in[8];
    const float* Wfc  = (const float*)d_in[9];
    const float* bfc  = (const float*)d_in[10];
    float* out = (float*)d_out;

    rnn2_pipek<<<dim3(512), dim3(128), 0, stream>>>(
        x, Wih0, Whh0, bih0, bhh0, Wih1, Whh1, bih1, bhh1, Wfc, bfc, out);
}